// Round 1
// 212.688 us; speedup vs baseline: 1.0073x; 1.0073x over previous
//
#include <hip/hip_runtime.h>
#include <hip/hip_bf16.h>
#include <stdint.h>

#define NNODES 50000
#define NEDGES 800000
#define LATENT 128
#define NTYPES 32
#define NTILES 25000   // NEDGES / 32 (32-edge tiles)
#define GRID_E 512     // 2 blocks/CU target

#define NODE_BLOCKS 782          // ceil(50000/64)
#define PREP_GRID (NODE_BLOCKS + 16 + 1)

typedef __bf16 bf16x8 __attribute__((ext_vector_type(8)));
typedef float floatx4 __attribute__((ext_vector_type(4)));
typedef unsigned int u32;

#if defined(__has_builtin)
#if __has_builtin(__builtin_amdgcn_global_load_lds)
#define HAS_GLD_LDS 1
#endif
#endif

// LDS-only barrier: waits lgkmcnt(0) but leaves vmcnt (async DMA) in flight.
__device__ __forceinline__ void lds_barrier() {
    asm volatile("s_waitcnt lgkmcnt(0)\n\ts_barrier" ::: "memory");
}

// async 16B/lane gather into LDS. lbase must be wave-uniform; HW deposits at lbase + lane*16.
__device__ __forceinline__ void gather16(const __hip_bfloat16* g, __hip_bfloat16* lbase, int lane) {
#ifdef HAS_GLD_LDS
    __builtin_amdgcn_global_load_lds(
        (const __attribute__((address_space(1))) u32*)(uintptr_t)g,
        (__attribute__((address_space(3))) u32*)(u32)(uintptr_t)lbase,
        16, 0, 0);
#else
    *(uint4*)(lbase + lane * 8) = *(const uint4*)g;
#endif
}

__device__ __forceinline__ int load_idx(const int* ei, bool i64, int half, size_t e) {
    size_t pos = (size_t)half * NEDGES + e;
    return i64 ? ei[2 * pos] : ei[pos];
}

// ---------------- prep kernel: node logits + z->bf16 cast + W1/W2 transpose, one launch.
// Node path (blocks 0..781): 64 nodes/block, thread = 4 nodes x 2 types register block
//   -> 6 LDS reads per 8 FMAs (old kernel: 2 reads/FMA) and Wn staged once per 64 nodes
//   (old: once per 8 nodes). LDS row stride 129: bank=(n+k)&31 -> worst 2-way (free, m136).
// W1 path (blocks 782..797): LDS-tiled 64x64 transpose, coalesced reads AND writes
//   (old kernel read W1 columns: 4B used per 64B line).
// W2 path (block 798): pack W2 -> W2Tp[16][256] (rows 8..15 zero).
__global__ __launch_bounds__(256) void prep_kernel(
    const float* __restrict__ z, const float* __restrict__ Wn, const float* __restrict__ bn,
    const float* __restrict__ W1, const float* __restrict__ W2,
    float* __restrict__ out, __hip_bfloat16* __restrict__ zbf,
    __hip_bfloat16* __restrict__ W1T, __hip_bfloat16* __restrict__ W2Tp) {
    __shared__ __align__(16) float pool[96 * 129];   // 49,536 B -> 3 blocks/CU
    int t = threadIdx.x;
    int b = blockIdx.x;

    if (b < NODE_BLOCKS) {
        float* zl = pool;                 // [64][129]
        float* wt = pool + 64 * 129;      // [32][129]
        int node0 = b * 64;
        // stage Wn transposed: wt[ty][k] = Wn[k][ty]; coalesced reads, banks distinct per wave
#pragma unroll
        for (int r = 0; r < 16; ++r) {
            int idx = t + 256 * r;
            wt[(idx & 31) * 129 + (idx >> 5)] = Wn[idx];
        }
        // stage z rows (coalesced float4) + fused bf16 cast out
#pragma unroll
        for (int r = 0; r < 8; ++r) {
            int idx = t + 256 * r;              // 2048 float4 = 64 rows x 128 floats
            int row = idx >> 5, c4 = idx & 31;
            int node = node0 + row;
            int srcn = node < NNODES ? node : (NNODES - 1);
            float4 v = *(const float4*)&z[(size_t)srcn * LATENT + c4 * 4];
            float* zp = zl + row * 129 + c4 * 4;   // stride 129: scalar stores (4B aligned only)
            zp[0] = v.x; zp[1] = v.y; zp[2] = v.z; zp[3] = v.w;
            if (node < NNODES) {
                __hip_bfloat16 o[4];
                o[0] = __float2bfloat16(v.x); o[1] = __float2bfloat16(v.y);
                o[2] = __float2bfloat16(v.z); o[3] = __float2bfloat16(v.w);
                *(uint2*)&zbf[(size_t)node * LATENT + c4 * 4] = *(const uint2*)o;
            }
        }
        __syncthreads();
        int ng = t & 15, tg = t >> 4;            // 16 node-groups x 16 type-groups
        const float* z0p = zl + (ng * 4 + 0) * 129;
        const float* z1p = zl + (ng * 4 + 1) * 129;
        const float* z2p = zl + (ng * 4 + 2) * 129;
        const float* z3p = zl + (ng * 4 + 3) * 129;
        const float* w0p = wt + (tg * 2 + 0) * 129;
        const float* w1p = wt + (tg * 2 + 1) * 129;
        float a00 = 0.f, a01 = 0.f, a10 = 0.f, a11 = 0.f;
        float a20 = 0.f, a21 = 0.f, a30 = 0.f, a31 = 0.f;
#pragma unroll 16
        for (int k = 0; k < 128; ++k) {
            float w0 = w0p[k], w1 = w1p[k];
            float x0 = z0p[k], x1 = z1p[k], x2 = z2p[k], x3 = z3p[k];
            a00 += x0 * w0; a01 += x0 * w1;
            a10 += x1 * w0; a11 += x1 * w1;
            a20 += x2 * w0; a21 += x2 * w1;
            a30 += x3 * w0; a31 += x3 * w1;
        }
        float bb0 = bn[tg * 2], bb1 = bn[tg * 2 + 1];
        float ar[4][2] = {{a00, a01}, {a10, a11}, {a20, a21}, {a30, a31}};
#pragma unroll
        for (int i = 0; i < 4; ++i) {
            int node = node0 + ng * 4 + i;
            if (node < NNODES) {
                float2 o; o.x = ar[i][0] + bb0; o.y = ar[i][1] + bb1;
                *(float2*)&out[(size_t)node * NTYPES + tg * 2] = o;   // 8B aligned (tg*2*4)
            }
        }
    } else if (b < NODE_BLOCKS + 16) {
        // W1T[n][k] = bf16(W1[k][n]); tile (bi,bj): rows k in [bi*64,..), cols n in [bj*64,..)
        float* tl = pool;                 // [64][65]; 65-pad -> transposed reads 2-way max
        int tb = b - NODE_BLOCKS, bi = tb >> 2, bj = tb & 3;
#pragma unroll
        for (int r = 0; r < 4; ++r) {
            int idx = t + 256 * r;        // 1024 float4 = 64 rows x 64 floats
            int row = idx >> 4, c4 = idx & 15;
            float4 v = *(const float4*)&W1[(size_t)(bi * 64 + row) * 256 + bj * 64 + c4 * 4];
            float* tp = tl + row * 65 + c4 * 4;
            tp[0] = v.x; tp[1] = v.y; tp[2] = v.z; tp[3] = v.w;
        }
        __syncthreads();
#pragma unroll
        for (int r = 0; r < 4; ++r) {
            int idx = t + 256 * r;
            int rr = idx >> 4, cq = idx & 15;    // output row rr = n-64-offset, col group cq
            __hip_bfloat16 o[4];
#pragma unroll
            for (int s = 0; s < 4; ++s) o[s] = __float2bfloat16(tl[(cq * 4 + s) * 65 + rr]);
            *(uint2*)&W1T[(size_t)(bj * 64 + rr) * 256 + bi * 64 + cq * 4] = *(const uint2*)o;
        }
    } else {
        // W2Tp[n][k] = bf16(W2[k][n]) for n<8, zero rows 8..15 (N=16 MFMA padding)
#pragma unroll
        for (int r = 0; r < 16; ++r) {
            int idx = t + 256 * r;               // 4096 = 16 x 256
            int n = idx >> 8, k = idx & 255;
            W2Tp[n * 256 + k] = __float2bfloat16(n < 8 ? W2[k * 8 + n] : 0.f);
        }
    }
}

// ---------------- fused edge MLP: 256-thread blocks, 32-edge tiles, 2 blocks/CU
// Layer-1 MFMA operands SWAPPED vs R2-R8: A = W1T (m=hidden), B = ef (n=edge).
// C-layout: row(quad*4+r) = hidden, col(l16) = edge -> epilogue packs 4 consecutive
// hidden values into one ds_write_b64 (was 32 scalar b16 writes with 4-way conflicts).
// ef layout: 32 rows(edges) x 32 chunks of 16B; phys chunk = logical ^ (edge & 7).
// VGPR calibration: cap = 2048 / (blocks * waves_per_block); (256,2) -> 256 cap, need ~210.
// T5: setprio(1) around MFMA clusters — 2 independent blocks/CU give phase diversity.
#define W2T_ROW 264

__global__ __launch_bounds__(256, 2) void edge_kernel(
    const __hip_bfloat16* __restrict__ zbf, const int* __restrict__ ei,
    const __hip_bfloat16* __restrict__ W1T, const float* __restrict__ b1,
    const __hip_bfloat16* __restrict__ W2T, const float* __restrict__ b2,
    float* __restrict__ out) {
    __shared__ __align__(16) __hip_bfloat16 ef[2][32 * 256];    // 2 x 16 KB
    __shared__ __align__(16) __hip_bfloat16 w2t[16 * W2T_ROW];  // 8448 B
    __shared__ int idx_lds[2][64];

    int t = threadIdx.x;                     // 0..255
    int lane = t & 63, wave = t >> 6;        // 4 waves
    int l16 = lane & 15, quad = lane >> 4;
    int sw = l16 & 7;                        // edge&7 for this lane's fragment rows
    int nb = wave * 64;                      // this wave's hidden slice [nb, nb+64)

    bool i64 = ((ei[1] | ei[3] | ei[5] | ei[7] | ei[9] | ei[11] | ei[13] | ei[15]) == 0);

    {   // stage W2T once: 512 chunks of 16B
        const uint4* src = (const uint4*)W2T;
#pragma unroll
        for (int i = 0; i < 2; ++i) {
            int p = t + 256 * i;
            int n = p >> 5, c = p & 31;
            *(uint4*)&w2t[n * W2T_ROW + c * 8] = src[p];
        }
    }

    // A panel: W1T rows for this wave's 64-hidden slice, K=256: 32 x bf16x8 = 128 VGPRs
    bf16x8 breg[4][8];
#pragma unroll
    for (int nt = 0; nt < 4; ++nt) {
        const __hip_bfloat16* rowp = W1T + (size_t)(nb + nt * 16 + l16) * 256 + quad * 8;
#pragma unroll
        for (int kt = 0; kt < 8; ++kt) breg[nt][kt] = *(const bf16x8*)(rowp + kt * 32);
    }

    // bias: b1 over hidden = nb + nt*16 + quad*4 + r  (4 aligned float4 loads)
    floatx4 b1v[4];
#pragma unroll
    for (int nt = 0; nt < 4; ++nt)
        b1v[nt] = *(const floatx4*)&b1[nb + nt * 16 + quad * 4];
    float b2v = (l16 < 8) ? b2[l16] : 0.f;

    int tile = blockIdx.x;
    if (t < 64) idx_lds[0][t] = load_idx(ei, i64, t >> 5, (size_t)tile * 32 + (t & 31));
    __syncthreads();   // idx_lds[0] + w2t visible
    {   // issue DMA gather tile0 -> ef[0]: 16 instr x 64 lanes x 16B = 16 KB
#pragma unroll
        for (int i = 0; i < 4; ++i) {
            int ii = wave * 4 + i;           // 0..15
            int s = ii * 64 + lane;
            int e = s >> 5, cp = s & 31;
            int c = cp ^ (e & 7);
            int node = idx_lds[0][(c >> 4) * 32 + e];
            gather16(zbf + (size_t)node * LATENT + (c & 15) * 8, &ef[0][ii * 512], lane);
        }
    }
    int v_idx = 0;
    {
        int t1 = tile + GRID_E; if (t1 >= NTILES) t1 = tile;
        if (t < 64) v_idx = load_idx(ei, i64, t >> 5, (size_t)t1 * 32 + (t & 31));
    }

    int cur = 0;
    for (; tile < NTILES; tile += GRID_E) {
        int nxt = cur ^ 1;
        if (t < 64) idx_lds[nxt][t] = v_idx;
        __syncthreads();   // B1: the one vmcnt(0) drain — DMA(cur) had a full tile to land

        {   // issue DMA gather (tile+G) -> ef[nxt]; stays in flight across B2/B3
#pragma unroll
            for (int i = 0; i < 4; ++i) {
                int ii = wave * 4 + i;
                int s = ii * 64 + lane;
                int e = s >> 5, cp = s & 31;
                int c = cp ^ (e & 7);
                int node = idx_lds[nxt][(c >> 4) * 32 + e];
                gather16(zbf + (size_t)node * LATENT + (c & 15) * 8, &ef[nxt][ii * 512], lane);
            }
        }
        {   // prefetch idx(tile + 2G)
            int t2 = tile + 2 * GRID_E; if (t2 >= NTILES) t2 = tile;
            if (t < 64) v_idx = load_idx(ei, i64, t >> 5, (size_t)t2 * 32 + (t & 31));
        }

        // ---- layer 1: A = breg (hidden), B = ef (edges); wave: M=64 hidden x N=32 edges
        const __hip_bfloat16* efc = ef[cur];
        floatx4 acc[4][2];
#pragma unroll
        for (int a = 0; a < 4; ++a)
#pragma unroll
            for (int b = 0; b < 2; ++b) acc[a][b] = floatx4{0.f, 0.f, 0.f, 0.f};

        __builtin_amdgcn_s_setprio(1);
#pragma unroll
        for (int kt = 0; kt < 8; ++kt) {
            bf16x8 bfrag[2];
#pragma unroll
            for (int et = 0; et < 2; ++et) {
                int e = et * 16 + l16;
                int chunk = e * 32 + ((kt * 4 + quad) ^ sw);
                bfrag[et] = *(const bf16x8*)&efc[chunk * 8];
            }
#pragma unroll
            for (int nt = 0; nt < 4; ++nt)
#pragma unroll
                for (int et = 0; et < 2; ++et)
                    acc[nt][et] = __builtin_amdgcn_mfma_f32_16x16x32_bf16(
                        breg[nt][kt], bfrag[et], acc[nt][et], 0, 0, 0);
        }
        __builtin_amdgcn_s_setprio(0);

        lds_barrier();   // B2: LDS-only — B-reads of ef[cur] done; DMA(nxt) not drained

        // ---- ReLU + bias, H -> ef[cur]: lane packs 4 consecutive hidden -> ds_write_b64
        __hip_bfloat16* efh = ef[cur];
#pragma unroll
        for (int nt = 0; nt < 4; ++nt)
#pragma unroll
            for (int et = 0; et < 2; ++et) {
                __hip_bfloat16 pk[4];
#pragma unroll
                for (int r = 0; r < 4; ++r) {
                    float v = acc[nt][et][r] + b1v[nt][r];
                    pk[r] = __float2bfloat16(v > 0.f ? v : 0.f);
                }
                int e = et * 16 + l16;
                int hb = nb + nt * 16 + quad * 4;        // aligned 4-elem group
                int phys = (hb >> 3) ^ (e & 7);
                *(uint2*)&efh[e * 256 + phys * 8 + (hb & 7)] = *(const uint2*)pk;
            }
        lds_barrier();   // B3: LDS-only — H visible

        // ---- layer 2: waves 0..1 each take 16 edges; A = H rows, B = w2t; N=16 (8 padded)
        if (wave < 2) {
            floatx4 acc2 = floatx4{0.f, 0.f, 0.f, 0.f};
            __builtin_amdgcn_s_setprio(1);
#pragma unroll
            for (int kt = 0; kt < 8; ++kt) {
                int e = wave * 16 + l16;
                int chunk = e * 32 + ((kt * 4 + quad) ^ sw);
                bf16x8 a2 = *(const bf16x8*)&efc[chunk * 8];
                bf16x8 b2f = *(const bf16x8*)&w2t[l16 * W2T_ROW + (kt * 4 + quad) * 8];
                acc2 = __builtin_amdgcn_mfma_f32_16x16x32_bf16(a2, b2f, acc2, 0, 0, 0);
            }
            __builtin_amdgcn_s_setprio(0);
            if (l16 < 8) {
                size_t e0 = (size_t)tile * 32;
#pragma unroll
                for (int r = 0; r < 4; ++r) {
                    size_t erow = e0 + wave * 16 + quad * 4 + r;
                    out[erow * 8 + l16] = acc2[r] + b2v;
                }
            }
        }
        cur ^= 1;
    }
}

extern "C" void kernel_launch(void* const* d_in, const int* in_sizes, int n_in,
                              void* d_out, int out_size, void* d_ws, size_t ws_size,
                              hipStream_t stream) {
    const float* z  = (const float*)d_in[0];
    const int* ei   = (const int*)d_in[1];
    const float* Wn = (const float*)d_in[2];
    const float* bn = (const float*)d_in[3];
    const float* W1 = (const float*)d_in[4];
    const float* b1 = (const float*)d_in[5];
    const float* W2 = (const float*)d_in[6];
    const float* b2 = (const float*)d_in[7];
    float* out = (float*)d_out;

    __hip_bfloat16* zbf  = (__hip_bfloat16*)d_ws;            // 6,400,000 bf16
    __hip_bfloat16* W1T  = zbf + (size_t)NNODES * LATENT;    // 65,536 bf16
    __hip_bfloat16* W2Tp = W1T + 256 * 256;                  // 4,096 bf16

    hipLaunchKernelGGL(prep_kernel, dim3(PREP_GRID), dim3(256), 0, stream,
                       z, Wn, bn, W1, W2, out, zbf, W1T, W2Tp);
    hipLaunchKernelGGL(edge_kernel, dim3(GRID_E), dim3(256), 0, stream,
                       zbf, ei, W1T, b1, W2Tp, b2, out + (size_t)NNODES * NTYPES);
}